// Round 1
// baseline (169.718 us; speedup 1.0000x reference)
//
#include <hip/hip_runtime.h>
#include <math.h>

#define NQ   1280
#define DD   256
#define CIN  64
#define HH   200
#define WW   200
#define BB   8
#define KW   576   // CIN * 9 taps per output channel
#define TPB  256

typedef float floatx4 __attribute__((ext_vector_type(4)));

__device__ __forceinline__ float wave_reduce(float v) {
#pragma unroll
    for (int off = 32; off > 0; off >>= 1) v += __shfl_down(v, off, 64);
    return v;
}

// Fused kernel: one block per batch, 1024 threads (16 waves).
//   phase 1: stage 4x4 zero-padded bilinear window for all 64 in-channels
//   phase 2: conv3x3 at the 4 corners, one wave per output channel (16 ch/wave),
//            ReLU + bilinear blend -> s_sh[c] (LDS only, no global round-trip)
//   phase 2b: aws[b] = sineembed(point_score[b]) . aws_w + aws_b (first 256 thr)
//   phase 3: t[b,d] = aws * dot(out_w[d,:], s_sh) + out_b[d]
__global__ __launch_bounds__(1024) void fused_prep_kernel(
    const float* __restrict__ navi,    // (B,2)
    const float* __restrict__ bev,     // (B,64,H,W)
    const float* __restrict__ pscore,  // (B,2)
    const float* __restrict__ aws_w,   // (256,)
    const float* __restrict__ aws_b,   // (1,)
    const float* __restrict__ conv_w,  // (256,64,3,3)
    const float* __restrict__ conv_b,  // (256,)
    const float* __restrict__ out_w,   // (256,256)
    const float* __restrict__ out_b,   // (256,)
    float* __restrict__ t_out)         // ws: (B,256)
{
    const int b    = blockIdx.x;
    const int tid  = threadIdx.x;
    const int lane = tid & 63;
    const int wave = tid >> 6;   // 0..15

    __shared__ float win[CIN * 16];  // 4x4 zero-padded window per in-channel
    __shared__ float s_sh[DD];       // sampled conv output per channel
    __shared__ float red[DD];        // aws reduction
    __shared__ float aws_sh;

    // ---- per-batch sample point ----
    float nx = navi[b * 2 + 0];
    float ny = navi[b * 2 + 1];
    float gx = (ny * (1.0f / 32.0f) + 1.0f) * 0.5f * (float)WW - 0.5f;
    float gy = (nx * (1.0f / 32.0f) + 1.0f) * 0.5f * (float)HH - 0.5f;
    float x0f = floorf(gx), y0f = floorf(gy);
    float wx1 = gx - x0f, wy1 = gy - y0f;
    int x0 = (int)x0f, y0 = (int)y0f;

    float cw[4];
    {
        float wx[2] = {1.0f - wx1, wx1};
        float wy[2] = {1.0f - wy1, wy1};
#pragma unroll
        for (int k = 0; k < 4; ++k) {
            int dx = k & 1, dy = k >> 1;
            float ixf = x0f + (float)dx, iyf = y0f + (float)dy;
            bool valid = (ixf >= 0.0f) && (ixf <= (float)(WW - 1)) &&
                         (iyf >= 0.0f) && (iyf <= (float)(HH - 1));
            cw[k] = wx[dx] * wy[dy] * (valid ? 1.0f : 0.0f);
        }
    }

    // ---- stage 4x4 zero-padded window, all 64 input channels (1 elem/thread) ----
    {
        int ci = tid >> 4, pos = tid & 15;
        int yy = y0 - 1 + (pos >> 2);
        int xx = x0 - 1 + (pos & 3);
        float v = 0.0f;
        if (yy >= 0 && yy < HH && xx >= 0 && xx < WW)
            v = bev[((size_t)b * CIN + ci) * (HH * WW) + (size_t)yy * WW + xx];
        win[tid] = v;
    }
    __syncthreads();

    // ---- conv: each wave owns 16 output channels; coalesced conv_w reads ----
    for (int jj = 0; jj < 16; ++jj) {
        const int c = (wave << 4) + jj;
        const float* wp = conv_w + (size_t)c * KW;
        float a0 = 0.f, a1 = 0.f, a2 = 0.f, a3 = 0.f;
#pragma unroll
        for (int i = 0; i < 9; ++i) {
            int k  = i * 64 + lane;
            int ci = k / 9;
            int r  = k - ci * 9;
            int ky = r / 3;
            int kx = r - ky * 3;
            int base = ci * 16 + ky * 4 + kx;
            float w = wp[k];
            a0 = fmaf(w, win[base],     a0);   // (y0,   x0)
            a1 = fmaf(w, win[base + 1], a1);   // (y0,   x0+1)
            a2 = fmaf(w, win[base + 4], a2);   // (y0+1, x0)
            a3 = fmaf(w, win[base + 5], a3);   // (y0+1, x0+1)
        }
        a0 = wave_reduce(a0);
        a1 = wave_reduce(a1);
        a2 = wave_reduce(a2);
        a3 = wave_reduce(a3);
        if (lane == 0) {
            float cb = conv_b[c];
            s_sh[c] = cw[0] * fmaxf(a0 + cb, 0.0f)
                    + cw[1] * fmaxf(a1 + cb, 0.0f)
                    + cw[2] * fmaxf(a2 + cb, 0.0f)
                    + cw[3] * fmaxf(a3 + cb, 0.0f);
        }
    }

    // ---- aws[b] partials (first 256 threads) ----
    if (tid < DD) {
        float psx = pscore[b * 2 + 0];
        float psy = pscore[b * 2 + 1];
        float p = (tid < 128) ? psy : psx;  // concat([embed(y), embed(x)])
        int j = (tid & 127) >> 1;
        float dimt = powf(10000.0f, (float)j * (1.0f / 64.0f));
        float arg = p * 6.283185307179586f / dimt;
        float e = (tid & 1) ? cosf(arg) : sinf(arg);
        red[tid] = e * aws_w[tid];
    }
    __syncthreads();   // also publishes s_sh for phase 3
    for (int off = 128; off > 0; off >>= 1) {
        if (tid < off) red[tid] += red[tid + off];
        __syncthreads();
    }
    if (tid == 0) aws_sh = red[0] + aws_b[0];
    __syncthreads();

    // ---- matvec: wave w owns d = w*16 .. w*16+15; coalesced out_w rows ----
    const float awsv = aws_sh;
    for (int jj = 0; jj < 16; ++jj) {
        const int d = (wave << 4) + jj;
        const float* wp = out_w + (size_t)d * DD;
        float sum = 0.0f;
#pragma unroll
        for (int i = 0; i < 4; ++i)
            sum = fmaf(wp[i * 64 + lane], s_sh[i * 64 + lane], sum);
        sum = wave_reduce(sum);
        if (lane == 0) t_out[b * DD + d] = awsv * sum + out_b[d];
    }
}

// Add kernel: out[b,q,d] = queries[b,q,d] + t[b,d].
// grid (320, 8): blockIdx.y = batch (no per-thread division); 1 float4/thread;
// non-temporal on the streaming tensors, t broadcast via L1/L2.
__global__ __launch_bounds__(256) void add_kernel(
    const floatx4* __restrict__ q4,
    const floatx4* __restrict__ t4,   // ws: (B, 64) floatx4
    floatx4* __restrict__ out4)
{
    const int b  = blockIdx.y;
    const int il = blockIdx.x * TPB + threadIdx.x;      // 0 .. 81919 within batch
    const int i  = b * (NQ * DD / 4) + il;
    floatx4 v = __builtin_nontemporal_load(&q4[i]);
    floatx4 tv = t4[b * (DD / 4) + (il & (DD / 4 - 1))];
    v += tv;
    __builtin_nontemporal_store(v, &out4[i]);
}

extern "C" void kernel_launch(void* const* d_in, const int* in_sizes, int n_in,
                              void* d_out, int out_size, void* d_ws, size_t ws_size,
                              hipStream_t stream) {
    const float* queries = (const float*)d_in[0];   // (B,NQ,256)
    const float* navi    = (const float*)d_in[1];   // (B,2)
    const float* bev     = (const float*)d_in[2];   // (B,64,200,200)
    // d_in[3] spatial_shape — unused (values 200,200)
    const float* pscore  = (const float*)d_in[4];   // (B,2)
    // d_in[5] aw_w, d_in[6] aw_b — dead (softmax over size-1 axis == 1)
    const float* aws_w   = (const float*)d_in[7];   // (1,256)
    const float* aws_b   = (const float*)d_in[8];   // (1,)
    const float* conv_w  = (const float*)d_in[9];   // (256,64,3,3)
    const float* conv_b  = (const float*)d_in[10];  // (256,)
    const float* out_w   = (const float*)d_in[11];  // (256,256)
    const float* out_b   = (const float*)d_in[12];  // (256,)

    // workspace layout (floats): t[B*256]  (s/aws now LDS-resident)
    float* t = (float*)d_ws;

    fused_prep_kernel<<<BB, 1024, 0, stream>>>(navi, bev, pscore, aws_w, aws_b,
                                               conv_w, conv_b, out_w, out_b, t);

    dim3 agrid(NQ * DD / 4 / TPB, BB);              // (320, 8)
    add_kernel<<<agrid, TPB, 0, stream>>>((const floatx4*)queries,
                                          (const floatx4*)t,
                                          (floatx4*)d_out);
}

// Round 2
// 142.995 us; speedup vs baseline: 1.1869x; 1.1869x over previous
//
#include <hip/hip_runtime.h>
#include <math.h>

#define NQ   1280
#define DD   256
#define CIN  64
#define HH   200
#define WW   200
#define BB   8
#define KW   576   // CIN * 9 taps per output channel
#define TPB  256

typedef float floatx4 __attribute__((ext_vector_type(4)));

__device__ __forceinline__ float wave_reduce(float v) {
#pragma unroll
    for (int off = 32; off > 0; off >>= 1) v += __shfl_down(v, off, 64);
    return v;
}

// Kernel 1: grid = B*64 blocks, 4 waves each; one wave per conv output channel.
// s[b,c] = bilinear blend of ReLU(conv3x3(bev)[c]) at the per-batch grid point.
// cgp==0 blocks also compute aws[b] = sineembed(point_score[b]).aws_w + aws_b.
// NOTE: blockIdx = b*64+cgp -> XCD = cgp%8, so all batches' reads of a given
// conv_w row-group share one XCD L2 (accidental but ideal; do not reorder).
__global__ __launch_bounds__(256) void conv_sample_kernel(
    const float* __restrict__ navi,    // (B,2)
    const float* __restrict__ bev,     // (B,64,H,W)
    const float* __restrict__ pscore,  // (B,2)
    const float* __restrict__ aws_w,   // (256,)
    const float* __restrict__ aws_b,   // (1,)
    const float* __restrict__ conv_w,  // (256,64,3,3)
    const float* __restrict__ conv_b,  // (256,)
    float* __restrict__ s_out,         // ws: (B,256)
    float* __restrict__ aws_out)       // ws: (B,)
{
    const int b    = blockIdx.x >> 6;
    const int cgp  = blockIdx.x & 63;
    const int tid  = threadIdx.x;
    const int lane = tid & 63;
    const int wave = tid >> 6;

    __shared__ float win[CIN * 16];  // 4x4 zero-padded window per in-channel
    __shared__ float red[DD];        // aws reduction

    // ---- per-batch sample point ----
    float nx = navi[b * 2 + 0];
    float ny = navi[b * 2 + 1];
    float gx = (ny * (1.0f / 32.0f) + 1.0f) * 0.5f * (float)WW - 0.5f;
    float gy = (nx * (1.0f / 32.0f) + 1.0f) * 0.5f * (float)HH - 0.5f;
    float x0f = floorf(gx), y0f = floorf(gy);
    float wx1 = gx - x0f, wy1 = gy - y0f;
    int x0 = (int)x0f, y0 = (int)y0f;

    float cw[4];
    {
        float wx[2] = {1.0f - wx1, wx1};
        float wy[2] = {1.0f - wy1, wy1};
#pragma unroll
        for (int k = 0; k < 4; ++k) {
            int dx = k & 1, dy = k >> 1;
            float ixf = x0f + (float)dx, iyf = y0f + (float)dy;
            bool valid = (ixf >= 0.0f) && (ixf <= (float)(WW - 1)) &&
                         (iyf >= 0.0f) && (iyf <= (float)(HH - 1));
            cw[k] = wx[dx] * wy[dy] * (valid ? 1.0f : 0.0f);
        }
    }

    // ---- stage 4x4 zero-padded window, all 64 input channels ----
    for (int idx = tid; idx < CIN * 16; idx += TPB) {
        int ci = idx >> 4, pos = idx & 15;
        int yy = y0 - 1 + (pos >> 2);
        int xx = x0 - 1 + (pos & 3);
        float v = 0.0f;
        if (yy >= 0 && yy < HH && xx >= 0 && xx < WW)
            v = bev[((size_t)b * CIN + ci) * (HH * WW) + (size_t)yy * WW + xx];
        win[idx] = v;
    }
    __syncthreads();

    // ---- one wave per output channel; coalesced conv_w reads, direct
    //      per-corner window reads (base, +1, +4, +5 -> ds_read2 pairs) ----
    const int c = cgp * 4 + wave;
    const float* wp = conv_w + (size_t)c * KW;
    float a0 = 0.f, a1 = 0.f, a2 = 0.f, a3 = 0.f;
#pragma unroll
    for (int i = 0; i < 9; ++i) {
        int k  = i * 64 + lane;
        int ci = k / 9;
        int r  = k - ci * 9;
        int ky = r / 3;
        int kx = r - ky * 3;
        int base = ci * 16 + ky * 4 + kx;
        float w = wp[k];
        a0 = fmaf(w, win[base],     a0);   // (y0,   x0)
        a1 = fmaf(w, win[base + 1], a1);   // (y0,   x0+1)
        a2 = fmaf(w, win[base + 4], a2);   // (y0+1, x0)
        a3 = fmaf(w, win[base + 5], a3);   // (y0+1, x0+1)
    }
    a0 = wave_reduce(a0);
    a1 = wave_reduce(a1);
    a2 = wave_reduce(a2);
    a3 = wave_reduce(a3);
    if (lane == 0) {
        float cb = conv_b[c];
        float v0 = fmaxf(a0 + cb, 0.0f);
        float v1 = fmaxf(a1 + cb, 0.0f);
        float v2 = fmaxf(a2 + cb, 0.0f);
        float v3 = fmaxf(a3 + cb, 0.0f);
        s_out[b * DD + c] = cw[0] * v0 + cw[1] * v1 + cw[2] * v2 + cw[3] * v3;
    }

    // ---- aws[b]: one block per batch (block-uniform branch) ----
    if (cgp == 0) {
        float psx = pscore[b * 2 + 0];
        float psy = pscore[b * 2 + 1];
        float p = (tid < 128) ? psy : psx;  // concat([embed(y), embed(x)])
        int j = (tid & 127) >> 1;
        float dimt = powf(10000.0f, (float)j * (1.0f / 64.0f));
        float arg = p * 6.283185307179586f / dimt;
        float e = (tid & 1) ? cosf(arg) : sinf(arg);
        red[tid] = e * aws_w[tid];
        __syncthreads();
        for (int off = 128; off > 0; off >>= 1) {
            if (tid < off) red[tid] += red[tid + off];
            __syncthreads();
        }
        if (tid == 0) aws_out[b] = red[0] + aws_b[0];
    }
}

// Kernel 2: grid = B*64 blocks, one wave per output dim; COALESCED out_w row
// reads (each row of out_w is read exactly once per batch: 2 MB total).
// t[b,d] = aws[b] * dot(out_w[d,:], s[b,:]) + out_b[d]
__global__ __launch_bounds__(256) void matvec_kernel(
    const float* __restrict__ out_w,   // (256,256)
    const float* __restrict__ out_b,   // (256,)
    const float* __restrict__ s_in,    // ws: (B,256)
    const float* __restrict__ aws_in,  // ws: (B,)
    float* __restrict__ t_out)         // ws: (B,256)
{
    const int b    = blockIdx.x >> 6;
    const int cgp  = blockIdx.x & 63;
    const int tid  = threadIdx.x;
    const int lane = tid & 63;
    const int wave = tid >> 6;

    __shared__ float s_sh[DD];
    s_sh[tid] = s_in[b * DD + tid];
    __syncthreads();

    const int d = cgp * 4 + wave;
    const float* wp = out_w + (size_t)d * DD;
    float sum = 0.0f;
#pragma unroll
    for (int i = 0; i < 4; ++i)
        sum = fmaf(wp[i * 64 + lane], s_sh[i * 64 + lane], sum);
    sum = wave_reduce(sum);
    if (lane == 0) t_out[b * DD + d] = aws_in[b] * sum + out_b[d];
}

// Kernel 3: out[b,q,d] = queries[b,q,d] + t[b,d].
// grid (320, 8): blockIdx.y = batch (no per-thread division); 1 float4/thread;
// non-temporal on the streaming tensors (no reuse), t broadcast via L1/L2.
__global__ __launch_bounds__(256) void add_kernel(
    const floatx4* __restrict__ q4,
    const floatx4* __restrict__ t4,   // ws: (B, 64) floatx4
    floatx4* __restrict__ out4)
{
    const int b  = blockIdx.y;
    const int il = blockIdx.x * TPB + threadIdx.x;      // 0 .. 81919 within batch
    const int i  = b * (NQ * DD / 4) + il;
    floatx4 v = __builtin_nontemporal_load(&q4[i]);
    floatx4 tv = t4[b * (DD / 4) + (il & (DD / 4 - 1))];
    v += tv;
    __builtin_nontemporal_store(v, &out4[i]);
}

extern "C" void kernel_launch(void* const* d_in, const int* in_sizes, int n_in,
                              void* d_out, int out_size, void* d_ws, size_t ws_size,
                              hipStream_t stream) {
    const float* queries = (const float*)d_in[0];   // (B,NQ,256)
    const float* navi    = (const float*)d_in[1];   // (B,2)
    const float* bev     = (const float*)d_in[2];   // (B,64,200,200)
    // d_in[3] spatial_shape — unused (values 200,200)
    const float* pscore  = (const float*)d_in[4];   // (B,2)
    // d_in[5] aw_w, d_in[6] aw_b — dead (softmax over size-1 axis == 1)
    const float* aws_w   = (const float*)d_in[7];   // (1,256)
    const float* aws_b   = (const float*)d_in[8];   // (1,)
    const float* conv_w  = (const float*)d_in[9];   // (256,64,3,3)
    const float* conv_b  = (const float*)d_in[10];  // (256,)
    const float* out_w   = (const float*)d_in[11];  // (256,256)
    const float* out_b   = (const float*)d_in[12];  // (256,)

    // workspace layout (floats): s[B*256] | aws[B ... pad to 256] | t[B*256]
    float* s   = (float*)d_ws;
    float* aws = s + BB * DD;
    float* t   = s + BB * DD + 256;                 // 16B-aligned

    conv_sample_kernel<<<BB * 64, TPB, 0, stream>>>(navi, bev, pscore, aws_w,
                                                    aws_b, conv_w, conv_b,
                                                    s, aws);
    matvec_kernel<<<BB * 64, TPB, 0, stream>>>(out_w, out_b, s, aws, t);

    dim3 agrid(NQ * DD / 4 / TPB, BB);              // (320, 8)
    add_kernel<<<agrid, TPB, 0, stream>>>((const floatx4*)queries,
                                          (const floatx4*)t,
                                          (floatx4*)d_out);
}